// Round 2
// 437.310 us; speedup vs baseline: 1.0154x; 1.0154x over previous
//
#include <hip/hip_runtime.h>

// NeighborlistVerletNsq: all-unique-pairs minimum-image displacement + distance
// + verlet-build / cutoff masks on MI355X.
//
// N = 6144 particles, P = N(N-1)/2 = 18,871,296 pairs.
// Output layout (flat f32, concatenated in reference return order):
//   [0,      3P)  r_ij  (row-major [P,3])
//   [3P,     4P)  d_ij
//   [4P,     5P)  in_build  (1.0f / 0.0f)
//   [5P,     6P)  in_cutoff (1.0f / 0.0f)
//
// V2 (resubmit after infra failure): 4 consecutive pairs per thread.
//  - f64-sqrt triangular index inversion amortized 4x (consecutive pairs
//    advance with ++j and a rare row-wrap branch)
//  - all stores are aligned float4 (P % 4 == 0, so the 3P/4P/5P region bases
//    and the 12*t / 4*t offsets are all 16B-aligned)
//  - per-pair arithmetic bitwise identical to V1 (same __f*_rn ops).

#define NPART 6144
#define PAIRS ((NPART * (NPART - 1)) / 2)   // 18,871,296  (fits int32)
#define NQUAD (PAIRS / 4)                   // 4,717,824 threads

// Replicates jnp.remainder(t, L) then -half, bitwise in fp32, for the
// restricted domain t in (-L/2, 3L/2) that holds because positions in [0, L).
__device__ __forceinline__ float min_image(float diff, float L, float half) {
    float t = __fadd_rn(diff, half);
    float m = t;
    if (t >= L)      m = __fsub_rn(t, L);
    else if (t < 0.f) m = __fadd_rn(t, L);
    return __fsub_rn(m, half);
}

__global__ __launch_bounds__(256) void nsq_pairs4_kernel(
    const float* __restrict__ pos,   // [N,3]
    const float* __restrict__ box,   // [3,3] diagonal
    float* __restrict__ out)
{
    int t = blockIdx.x * blockDim.x + threadIdx.x;
    if (t >= NQUAD) return;
    const int p0 = t << 2;                        // first of 4 pairs

    // ---- invert p0 -> (i, j), i < j, np.triu_indices order (once per 4) ----
    const double A = (double)(2 * NPART - 1);
    double disc = A * A - 8.0 * (double)p0;
    int i = (int)((A - sqrt(disc)) * 0.5);
    i = max(0, min(i, NPART - 2));
    int rs = i * NPART - (i * (i + 1)) / 2;       // row_start(i)
    int rlen = NPART - 1 - i;
    while (p0 >= rs + rlen) { rs += rlen; ++i; rlen = NPART - 1 - i; }
    while (p0 < rs)         { rs -= (NPART - i); --i; rlen = NPART - 1 - i; }
    int j = i + 1 + (p0 - rs);

    // ---- box lengths (uniform) ----
    float Lx = box[0], Ly = box[4], Lz = box[8];
    float hx = __fmul_rn(Lx, 0.5f);
    float hy = __fmul_rn(Ly, 0.5f);
    float hz = __fmul_rn(Lz, 0.5f);

    float xi = pos[3 * i + 0], yi = pos[3 * i + 1], zi = pos[3 * i + 2];

    float rbuf[12], dbuf[4], b1[4], b2[4];

    #pragma unroll
    for (int k = 0; k < 4; ++k) {
        if (k > 0) {
            ++j;
            if (j >= NPART) {                      // rare: row wrap
                ++i; j = i + 1;
                xi = pos[3 * i + 0]; yi = pos[3 * i + 1]; zi = pos[3 * i + 2];
            }
        }
        float xj = pos[3 * j + 0], yj = pos[3 * j + 1], zj = pos[3 * j + 2];

        float rx = min_image(__fsub_rn(xi, xj), Lx, hx);
        float ry = min_image(__fsub_rn(yi, yj), Ly, hy);
        float rz = min_image(__fsub_rn(zi, zj), Lz, hz);

        float s = __fadd_rn(__fadd_rn(__fmul_rn(rx, rx), __fmul_rn(ry, ry)),
                            __fmul_rn(rz, rz));
        float d = sqrtf(s);

        rbuf[3 * k + 0] = rx;
        rbuf[3 * k + 1] = ry;
        rbuf[3 * k + 2] = rz;
        dbuf[k] = d;
        b1[k] = (d <  0.6f) ? 1.0f : 0.0f;         // CUTOFF + SKIN
        b2[k] = (d <= 0.5f) ? 1.0f : 0.0f;         // CUTOFF
    }

    // ---- vectorized stores: 6x dwordx4, all 16B-aligned ----
    const int P = PAIRS;
    float4* rq = reinterpret_cast<float4*>(out + (size_t)12 * t);
    rq[0] = make_float4(rbuf[0], rbuf[1], rbuf[2],  rbuf[3]);
    rq[1] = make_float4(rbuf[4], rbuf[5], rbuf[6],  rbuf[7]);
    rq[2] = make_float4(rbuf[8], rbuf[9], rbuf[10], rbuf[11]);

    *reinterpret_cast<float4*>(out + (size_t)3 * P + 4 * (size_t)t) =
        make_float4(dbuf[0], dbuf[1], dbuf[2], dbuf[3]);
    *reinterpret_cast<float4*>(out + (size_t)4 * P + 4 * (size_t)t) =
        make_float4(b1[0], b1[1], b1[2], b1[3]);
    *reinterpret_cast<float4*>(out + (size_t)5 * P + 4 * (size_t)t) =
        make_float4(b2[0], b2[1], b2[2], b2[3]);
}

extern "C" void kernel_launch(void* const* d_in, const int* in_sizes, int n_in,
                              void* d_out, int out_size, void* d_ws, size_t ws_size,
                              hipStream_t stream) {
    const float* pos = (const float*)d_in[0];   // [6144, 3] f32
    const float* box = (const float*)d_in[1];   // [3, 3]  f32
    float* out = (float*)d_out;                 // 6P f32

    const int block = 256;
    const int grid = (NQUAD + block - 1) / block;  // 18,429 blocks
    nsq_pairs4_kernel<<<grid, block, 0, stream>>>(pos, box, out);
}